// Round 4
// baseline (288.746 us; speedup 1.0000x reference)
//
#include <hip/hip_runtime.h>

#define H    128
#define NB   4
#define NR   8
#define DT   32    // dst-nodes per block in fused kernel

typedef __attribute__((ext_vector_type(8))) short short8;
typedef __attribute__((ext_vector_type(4))) float f32x4;

static __device__ __forceinline__ unsigned short f2bf(float f) {
    unsigned u = __float_as_uint(f);
    unsigned r = (u + 0x7fffu + ((u >> 16) & 1u)) >> 16;
    return (unsigned short)r;
}
static __device__ __forceinline__ float bf_lo(unsigned v) {
    return __uint_as_float((v & 0xffffu) << 16);
}
static __device__ __forceinline__ float bf_hi(unsigned v) {
    return __uint_as_float(v & 0xffff0000u);
}

// ---------------- zero int array ----------------
__global__ __launch_bounds__(256) void zero_i(int* __restrict__ p, int n) {
    int i = blockIdx.x * 256 + threadIdx.x;
    if (i < n) p[i] = 0;
}

// ---------------- histogram over key = dst*8 + etype ----------------
__global__ __launch_bounds__(256) void hist_key(const int* __restrict__ dst,
                                                const int* __restrict__ etype,
                                                int* __restrict__ counts, int E) {
    int e = blockIdx.x * 256 + threadIdx.x;
    if (e < E) atomicAdd(&counts[dst[e] * NR + etype[e]], 1);
}

// ---------------- hierarchical scan stage 1 ----------------
__global__ __launch_bounds__(1024) void scan_blocks(const int* __restrict__ counts,
                                                    int* __restrict__ partial,
                                                    int* __restrict__ blocksums, int n) {
    __shared__ int buf[1024];
    int tid = threadIdx.x;
    int i = blockIdx.x * 1024 + tid;
    buf[tid] = (i < n) ? counts[i] : 0;
    __syncthreads();
#pragma unroll
    for (int off = 1; off < 1024; off <<= 1) {
        int t = (tid >= off) ? buf[tid - off] : 0;
        __syncthreads();
        buf[tid] += t;
        __syncthreads();
    }
    if (i < n) partial[i] = buf[tid];
    if (tid == 1023) blocksums[blockIdx.x] = buf[1023];
}

// ---------------- stage 2: single-block scan of block sums (nb <= 512) ----
__global__ __launch_bounds__(512) void scan_carry(int* __restrict__ blocksums, int nb) {
    __shared__ int buf[512];
    int tid = threadIdx.x;
    buf[tid] = (tid < nb) ? blocksums[tid] : 0;
    __syncthreads();
#pragma unroll
    for (int off = 1; off < 512; off <<= 1) {
        int t = (tid >= off) ? buf[tid - off] : 0;
        __syncthreads();
        buf[tid] += t;
        __syncthreads();
    }
    if (tid < nb) blocksums[tid] = buf[tid];
}

// ---------------- stage 3: add carry, emit offs[0..n] ----------------
__global__ __launch_bounds__(256) void scan_add(const int* __restrict__ partial,
                                                const int* __restrict__ blocksums,
                                                int* __restrict__ offs, int n) {
    int i = blockIdx.x * 256 + threadIdx.x;
    if (i >= n) return;
    int b = i >> 10;
    int carry = (b > 0) ? blocksums[b - 1] : 0;
    offs[i + 1] = partial[i] + carry;
    if (i == 0) offs[0] = 0;
}

// ---------------- scatter edges into CSR order (key = dst*8+etype) ----------------
__global__ __launch_bounds__(256) void scatter_edges(
        const int* __restrict__ src, const int* __restrict__ dst,
        const int* __restrict__ etype, const float* __restrict__ norm,
        const int* __restrict__ offs, int* __restrict__ counts,
        int* __restrict__ ridx, float* __restrict__ rnorm, int E) {
    int e = blockIdx.x * 256 + threadIdx.x;
    if (e >= E) return;
    int r = etype[e];
    int key = dst[e] * NR + r;
    int pos = offs[key] + atomicSub(&counts[key], 1) - 1;
    ridx[pos]  = (r << 28) | src[e];
    rnorm[pos] = norm[e];
}

// ---------------- f32 -> bf16 convert ----------------
__global__ __launch_bounds__(256) void convert_bf16(const float* __restrict__ in,
                                                    unsigned short* __restrict__ out, int n4) {
    int i = blockIdx.x * 256 + threadIdx.x;
    if (i >= n4) return;
    float4 v = ((const float4*)in)[i];
    ushort4 o;
    o.x = f2bf(v.x); o.y = f2bf(v.y); o.z = f2bf(v.z); o.w = f2bf(v.w);
    ((ushort4*)out)[i] = o;
}

// ---- W build: Wt2[l][o][r*128+d] = bf16(sum_b comp[r,b]*basis[b][d][o]) ----
__global__ __launch_bounds__(128) void make_wt(
        const float* __restrict__ basis0, const float* __restrict__ comp0,
        const float* __restrict__ basis1, const float* __restrict__ comp1,
        unsigned short* __restrict__ Wt2) {
    int r = blockIdx.x;        // 0..7
    int d = blockIdx.y;        // 0..127
    int l = blockIdx.z;        // 0..1
    int o = threadIdx.x;       // 0..127
    const float* basis = l ? basis1 : basis0;
    const float* comp  = l ? comp1  : comp0;
    float s = 0.f;
#pragma unroll
    for (int b = 0; b < NB; ++b)
        s += comp[r * NB + b] * basis[((size_t)b * H + d) * H + o];
    Wt2[(((size_t)l * H + o) * (NR * H)) + r * H + d] = f2bf(s);
}

// ---------------- fused layer: LDS-agg + MFMA GEMM + bias + relu ----------------
// block = 512 threads (8 waves), DT=32 dst nodes.
// Phase A: wave w aggregates nodes w*4..w*4+3 into LDS AggTile[32][1024] bf16 (swizzled).
// Phase B: wave w computes output cols [w*16, w*16+16) for all 32 rows, K=1024.
__global__ __launch_bounds__(512) void fused_layer(
        const unsigned short* __restrict__ hin,   // [M][128] bf16 (gather source)
        const int* __restrict__ offs,             // [M*8+1]
        const int* __restrict__ ridx,             // packed (etype<<28)|src, CSR order
        const float* __restrict__ rnorm,
        const unsigned short* __restrict__ Wt2,   // [128 o][1024 k] bf16
        const float* __restrict__ bias,
        void* __restrict__ outp, int M, int write_bf16) {
    __shared__ char lds[DT * 2048];               // 64 KB: AggTile[32][1024] bf16
    const int tid  = threadIdx.x;
    const int wid  = tid >> 6;
    const int lane = tid & 63;
    const int v0   = blockIdx.x * DT;

    // ---------------- phase A: aggregate ----------------
#pragma unroll
    for (int i = 0; i < 4; ++i) {
        const int vl = wid * 4 + i;
        const int v  = v0 + vl;
        char* row = lds + vl * 2048;
        // zero this node's row (64 lanes x 32B)
        *(f32x4*)(row + lane * 32)      = (f32x4){0.f, 0.f, 0.f, 0.f};
        *(f32x4*)(row + lane * 32 + 16) = (f32x4){0.f, 0.f, 0.f, 0.f};
        if (v >= M) continue;
        const int nbeg = offs[v * NR];
        const int nend = offs[v * NR + NR];
        if (nbeg == nend) continue;

        float ax = 0.f, ay = 0.f;
        int rcur = -1;
#define FLUSH() { unsigned pk = (unsigned)f2bf(ax) | ((unsigned)f2bf(ay) << 16); \
                  *(unsigned*)(row + ((rcur * 256 + lane * 4) ^ ((vl & 7) << 4))) = pk; }
        for (int base = nbeg; base < nend; base += 64) {
            const int cnt = min(64, nend - base);
            int p = 0; float w = 0.f;
            if (lane < cnt) { p = ridx[base + lane]; w = rnorm[base + lane]; }
            int j = 0;
            for (; j + 4 <= cnt; j += 4) {
                int   p0 = __shfl(p, j),     p1 = __shfl(p, j + 1);
                int   p2 = __shfl(p, j + 2), p3 = __shfl(p, j + 3);
                float w0 = __shfl(w, j),     w1 = __shfl(w, j + 1);
                float w2 = __shfl(w, j + 2), w3 = __shfl(w, j + 3);
                unsigned u0 = *(const unsigned*)(hin + (size_t)(p0 & 0x0FFFFFFF) * H + lane * 2);
                unsigned u1 = *(const unsigned*)(hin + (size_t)(p1 & 0x0FFFFFFF) * H + lane * 2);
                unsigned u2 = *(const unsigned*)(hin + (size_t)(p2 & 0x0FFFFFFF) * H + lane * 2);
                unsigned u3 = *(const unsigned*)(hin + (size_t)(p3 & 0x0FFFFFFF) * H + lane * 2);
                int r0 = p0 >> 28, r1 = p1 >> 28, r2 = p2 >> 28, r3 = p3 >> 28;
                if (r0 != rcur) { if (rcur >= 0) FLUSH(); ax = 0.f; ay = 0.f; rcur = r0; }
                ax += w0 * bf_lo(u0); ay += w0 * bf_hi(u0);
                if (r1 != rcur) { FLUSH(); ax = 0.f; ay = 0.f; rcur = r1; }
                ax += w1 * bf_lo(u1); ay += w1 * bf_hi(u1);
                if (r2 != rcur) { FLUSH(); ax = 0.f; ay = 0.f; rcur = r2; }
                ax += w2 * bf_lo(u2); ay += w2 * bf_hi(u2);
                if (r3 != rcur) { FLUSH(); ax = 0.f; ay = 0.f; rcur = r3; }
                ax += w3 * bf_lo(u3); ay += w3 * bf_hi(u3);
            }
            for (; j < cnt; ++j) {
                int   pj = __shfl(p, j);
                float wj = __shfl(w, j);
                unsigned u = *(const unsigned*)(hin + (size_t)(pj & 0x0FFFFFFF) * H + lane * 2);
                int rj = pj >> 28;
                if (rj != rcur) { if (rcur >= 0) FLUSH(); ax = 0.f; ay = 0.f; rcur = rj; }
                ax += wj * bf_lo(u); ay += wj * bf_hi(u);
            }
        }
        if (rcur >= 0) FLUSH();
#undef FLUSH
    }
    __syncthreads();

    // ---------------- phase B: [32 x 1024] @ [1024 x 128] ----------------
    const int n0 = wid * 16;           // this wave's 16 output cols
    const int lr = lane & 15;
    const int lg = lane >> 4;
    const char* bbase = (const char*)Wt2 + (size_t)(n0 + lr) * (NR * H) * 2;
    const int swz = (lr & 7) << 4;     // row swizzle (rows 0..31: row&7 == lr&7)

    f32x4 acc0 = (f32x4){0.f, 0.f, 0.f, 0.f};
    f32x4 acc1 = (f32x4){0.f, 0.f, 0.f, 0.f};
#pragma unroll 4
    for (int ks = 0; ks < 32; ++ks) {
        const int kb = ks * 64 + lg * 16;
        short8 b  = *(const short8*)(bbase + kb);
        short8 a0 = *(const short8*)(lds + (lr)      * 2048 + (kb ^ swz));
        short8 a1 = *(const short8*)(lds + (16 + lr) * 2048 + (kb ^ swz));
        acc0 = __builtin_amdgcn_mfma_f32_16x16x32_bf16(a0, b, acc0, 0, 0, 0);
        acc1 = __builtin_amdgcn_mfma_f32_16x16x32_bf16(a1, b, acc1, 0, 0, 0);
    }

    const float bcol = bias[n0 + lr];
#pragma unroll
    for (int m = 0; m < 2; ++m) {
        const f32x4 a = m ? acc1 : acc0;
#pragma unroll
        for (int j = 0; j < 4; ++j) {
            const int rl   = m * 16 + lg * 4 + j;
            const int grow = v0 + rl;
            if (grow < M) {
                float val = fmaxf(a[j] + bcol, 0.f);
                if (write_bf16)
                    ((unsigned short*)outp)[(size_t)grow * H + n0 + lr] = f2bf(val);
                else
                    ((float*)outp)[(size_t)grow * H + n0 + lr] = val;
            }
        }
    }
}

extern "C" void kernel_launch(void* const* d_in, const int* in_sizes, int n_in,
                              void* d_out, int out_size, void* d_ws, size_t ws_size,
                              hipStream_t stream) {
    const float* feats  = (const float*)d_in[0];
    const int*   src    = (const int*)  d_in[1];
    const int*   dst    = (const int*)  d_in[2];
    const int*   etype  = (const int*)  d_in[3];
    const float* norm   = (const float*)d_in[4];
    const float* basis0 = (const float*)d_in[5];
    const float* comp0  = (const float*)d_in[6];
    const float* bias0  = (const float*)d_in[7];
    const float* basis1 = (const float*)d_in[8];
    const float* comp1  = (const float*)d_in[9];
    const float* bias1  = (const float*)d_in[10];
    float* out = (float*)d_out;

    const int M = in_sizes[0] / H;     // 50000
    const int E = in_sizes[1];         // 600000
    const int NK = M * NR;             // 400000 CSR segments

    // workspace carve-up (256B aligned)
    char* ws = (char*)d_ws;
    size_t cur = 0;
    auto take = [&](size_t bytes) { void* p = ws + cur; cur += (bytes + 255) & ~(size_t)255; return p; };
    unsigned short* hbf   = (unsigned short*)take((size_t)M * H * 2);          // 12.8 MB
    unsigned short* h1bf  = (unsigned short*)take((size_t)M * H * 2);          // 12.8 MB
    unsigned short* Wt2   = (unsigned short*)take((size_t)2 * H * NR * H * 2); // 512 KB
    int*   counts  = (int*)take((size_t)NK * 4);
    int*   offs    = (int*)take((size_t)(NK + 1) * 4);
    int*   partial = (int*)take((size_t)NK * 4);
    int*   bsums   = (int*)take((size_t)512 * 4);
    int*   ridx    = (int*)take((size_t)E * 4);
    float* rnorm   = (float*)take((size_t)E * 4);

    dim3 blk(256);
    int kb  = (NK + 255) / 256;          // 1563
    int eb  = (E + 255) / 256;           // 2344
    int n4  = M * H / 4;
    int cb  = (n4 + 255) / 256;
    int nsb = (NK + 1023) / 1024;        // 391 (<512)
    int fb  = (M + DT - 1) / DT;         // 1563

    // ---- graph prep (stateless every call) ----
    zero_i       <<<kb, blk, 0, stream>>>(counts, NK);
    hist_key     <<<eb, blk, 0, stream>>>(dst, etype, counts, E);
    scan_blocks  <<<nsb, 1024, 0, stream>>>(counts, partial, bsums, NK);
    scan_carry   <<<1, 512, 0, stream>>>(bsums, nsb);
    scan_add     <<<kb, blk, 0, stream>>>(partial, bsums, offs, NK);
    scatter_edges<<<eb, blk, 0, stream>>>(src, dst, etype, norm, offs, counts, ridx, rnorm, E);
    convert_bf16 <<<cb, blk, 0, stream>>>(feats, hbf, n4);
    make_wt      <<<dim3(NR, H, 2), 128, 0, stream>>>(basis0, comp0, basis1, comp1, Wt2);

    // ---- layer 0: h1 = relu(agg(feats) @ W + bias0), bf16 out ----
    fused_layer<<<fb, 512, 0, stream>>>(hbf, offs, ridx, rnorm, Wt2, bias0, h1bf, M, 1);
    // ---- layer 1: out = relu(agg(h1) @ W + bias1), f32 out ----
    fused_layer<<<fb, 512, 0, stream>>>(h1bf, offs, ridx, rnorm,
                                        Wt2 + (size_t)H * NR * H, bias1, out, M, 0);
}